// Round 1
// baseline (2363.597 us; speedup 1.0000x reference)
//
#include <hip/hip_runtime.h>
#include <math.h>

// MinVQVAE1D forward, f32 baseline.
// N=16384, D=1024, H=1024, L=256, K=4096.
// out = [x_pred (N*D) | z_discrete as float 0/1 (N*K) | loss (1)]

#define TS 128
#define BKK 16

__device__ __forceinline__ float gelu_f(float v) {
    return 0.5f * v * (1.0f + erff(v * 0.70710678118654752f));
}

// A [M,Kd] row-major.
// BT=false: B [Kd,Nn] row-major.  BT=true: B [Nn,Kd] row-major (B^T gemm).
// EPI: 0 = +bias, 1 = gelu(+bias), 2 = sigmoid(+bias) + SSE vs xref,
//      3 = bias[col] - 2*acc (VQ scores; bias = ||e_k||^2)
template<int EPI, bool BT>
__global__ __launch_bounds__(256)
void gemm128(const float* __restrict__ A, const float* __restrict__ B,
             const float* __restrict__ bias, float* __restrict__ C,
             int M, int Kd, int Nn,
             const float* __restrict__ xref, float* __restrict__ ssePartial)
{
    __shared__ float As[BKK][TS];
    __shared__ float Bs[BKK][TS];
    __shared__ float red[256];

    const int tid = threadIdx.x;
    const int m0 = blockIdx.y * TS;
    const int n0 = blockIdx.x * TS;
    const int tc = tid & 15;   // column group
    const int tr = tid >> 4;   // row group

    float acc[8][8];
    #pragma unroll
    for (int i = 0; i < 8; i++)
        #pragma unroll
        for (int j = 0; j < 8; j++) acc[i][j] = 0.0f;

    for (int k0 = 0; k0 < Kd; k0 += BKK) {
        // ---- load A tile (128 rows x 16 cols), store transposed As[k][m]
        #pragma unroll
        for (int h = 0; h < 2; h++) {
            int idx = tid + h * 256;
            int ar = idx >> 2;
            int ac = (idx & 3) * 4;
            const float4 v = *(const float4*)(A + (size_t)(m0 + ar) * Kd + k0 + ac);
            As[ac + 0][ar] = v.x; As[ac + 1][ar] = v.y;
            As[ac + 2][ar] = v.z; As[ac + 3][ar] = v.w;
        }
        // ---- load B tile
        if (!BT) {
            // B[k0..k0+16][n0..n0+128]
            #pragma unroll
            for (int h = 0; h < 2; h++) {
                int idx = tid + h * 256;
                int br = idx >> 5;
                int bc = (idx & 31) * 4;
                const float4 v = *(const float4*)(B + (size_t)(k0 + br) * Nn + n0 + bc);
                *(float4*)&Bs[br][bc] = v;
            }
        } else {
            // B[n0..n0+128][k0..k0+16], store transposed Bs[k][n]
            #pragma unroll
            for (int h = 0; h < 2; h++) {
                int idx = tid + h * 256;
                int nr = idx >> 2;
                int kc = (idx & 3) * 4;
                const float4 v = *(const float4*)(B + (size_t)(n0 + nr) * Kd + k0 + kc);
                Bs[kc + 0][nr] = v.x; Bs[kc + 1][nr] = v.y;
                Bs[kc + 2][nr] = v.z; Bs[kc + 3][nr] = v.w;
            }
        }
        __syncthreads();

        #pragma unroll
        for (int k = 0; k < BKK; k++) {
            float4 a0 = *(const float4*)&As[k][tr * 8];
            float4 a1 = *(const float4*)&As[k][tr * 8 + 4];
            float4 b0 = *(const float4*)&Bs[k][tc * 8];
            float4 b1 = *(const float4*)&Bs[k][tc * 8 + 4];
            float av[8] = {a0.x, a0.y, a0.z, a0.w, a1.x, a1.y, a1.z, a1.w};
            float bv[8] = {b0.x, b0.y, b0.z, b0.w, b1.x, b1.y, b1.z, b1.w};
            #pragma unroll
            for (int i = 0; i < 8; i++)
                #pragma unroll
                for (int j = 0; j < 8; j++)
                    acc[i][j] = fmaf(av[i], bv[j], acc[i][j]);
        }
        __syncthreads();
    }

    // ---- epilogue
    float lsse = 0.0f;
    #pragma unroll
    for (int i = 0; i < 8; i++) {
        int row = m0 + tr * 8 + i;
        float vals[8];
        #pragma unroll
        for (int j = 0; j < 8; j++) {
            int col = n0 + tc * 8 + j;
            float v = acc[i][j];
            if (EPI == 3) {
                v = bias[col] - 2.0f * v;
            } else {
                v += bias[col];
                if (EPI == 1) v = gelu_f(v);
                else if (EPI == 2) {
                    v = 1.0f / (1.0f + expf(-v));
                    float d = xref[(size_t)row * Nn + col] - v;
                    lsse += d * d;
                }
            }
            vals[j] = v;
        }
        float* crow = C + (size_t)row * Nn + n0 + tc * 8;
        *(float4*)(crow)     = make_float4(vals[0], vals[1], vals[2], vals[3]);
        *(float4*)(crow + 4) = make_float4(vals[4], vals[5], vals[6], vals[7]);
    }

    if (EPI == 2) {
        red[tid] = lsse;
        __syncthreads();
        for (int s = 128; s > 0; s >>= 1) {
            if (tid < s) red[tid] += red[tid + s];
            __syncthreads();
        }
        if (tid == 0) ssePartial[blockIdx.y * gridDim.x + blockIdx.x] = red[0];
    }
}

// ||e_k||^2 per codebook row (L=256)
__global__ __launch_bounds__(64)
void colnorm(const float* __restrict__ pool, float* __restrict__ c)
{
    int r = blockIdx.x;
    int lane = threadIdx.x;
    float4 v = *(const float4*)(pool + (size_t)r * 256 + lane * 4);
    float s = v.x * v.x + v.y * v.y + v.z * v.z + v.w * v.w;
    #pragma unroll
    for (int o = 32; o > 0; o >>= 1) s += __shfl_down(s, o);
    if (lane == 0) c[r] = s;
}

// Per-row argmin over scores (in z_discrete region), overwrite with one-hot,
// gather z_q, per-row VQ loss partial.
__global__ __launch_bounds__(256)
void argmin_onehot(float* __restrict__ scores, const float* __restrict__ zE,
                   const float* __restrict__ pool, float* __restrict__ zq,
                   float* __restrict__ vqPartial)
{
    const int r = blockIdx.x;
    const int tid = threadIdx.x;
    float* srow = scores + (size_t)r * 4096;

    float best = INFINITY;
    int bidx = 0x7fffffff;
    for (int k = tid; k < 4096; k += 256) {
        float v = srow[k];
        if (v < best) { best = v; bidx = k; }   // strict < keeps first min
    }
    __shared__ float sv[256];
    __shared__ int si[256];
    sv[tid] = best; si[tid] = bidx;
    __syncthreads();
    for (int s = 128; s > 0; s >>= 1) {
        if (tid < s) {
            float v2 = sv[tid + s]; int i2 = si[tid + s];
            if (v2 < sv[tid] || (v2 == sv[tid] && i2 < si[tid])) {
                sv[tid] = v2; si[tid] = i2;
            }
        }
        __syncthreads();
    }
    const int kbest = si[0];
    __syncthreads();

    for (int k = tid; k < 4096; k += 256)
        srow[k] = (k == kbest) ? 1.0f : 0.0f;

    // gather z_q row + vq loss partial (L=256, one element per thread)
    float zqv = pool[(size_t)kbest * 256 + tid];
    zq[(size_t)r * 256 + tid] = zqv;
    float d = zE[(size_t)r * 256 + tid] - zqv;
    sv[tid] = d * d;
    __syncthreads();
    for (int s = 128; s > 0; s >>= 1) {
        if (tid < s) sv[tid] += sv[tid + s];
        __syncthreads();
    }
    if (tid == 0) vqPartial[r] = sv[0];
}

__global__ __launch_bounds__(256)
void loss_final(const float* __restrict__ sseP, int nP,
                const float* __restrict__ vqP, int nV,
                float* __restrict__ out)
{
    int tid = threadIdx.x;
    float sx = 0.0f, svq = 0.0f;
    for (int i = tid; i < nP; i += 256) sx += sseP[i];
    for (int i = tid; i < nV; i += 256) svq += vqP[i];
    __shared__ float a[256], b[256];
    a[tid] = sx; b[tid] = svq;
    __syncthreads();
    for (int s = 128; s > 0; s >>= 1) {
        if (tid < s) { a[tid] += a[tid + s]; b[tid] += b[tid + s]; }
        __syncthreads();
    }
    if (tid == 0) out[0] = (a[0] + 1.25f * b[0]) / 16384.0f;
}

extern "C" void kernel_launch(void* const* d_in, const int* in_sizes, int n_in,
                              void* d_out, int out_size, void* d_ws, size_t ws_size,
                              hipStream_t stream)
{
    const float* x    = (const float*)d_in[0];
    const float* pool = (const float*)d_in[1];
    const float* ew1  = (const float*)d_in[2];
    const float* eb1  = (const float*)d_in[3];
    const float* ew2  = (const float*)d_in[4];
    const float* eb2  = (const float*)d_in[5];
    const float* ew3  = (const float*)d_in[6];
    const float* eb3  = (const float*)d_in[7];
    const float* dw1  = (const float*)d_in[8];
    const float* db1  = (const float*)d_in[9];
    const float* dw2  = (const float*)d_in[10];
    const float* db2  = (const float*)d_in[11];
    const float* dw3  = (const float*)d_in[12];
    const float* db3  = (const float*)d_in[13];

    const int N = 16384, D = 1024, H = 1024, L = 256, K = 4096;

    float* out   = (float*)d_out;
    float* xpred = out;                               // N*D
    float* zdisc = out + (size_t)N * D;               // N*K (scores, then one-hot)
    float* lossp = out + (size_t)N * D + (size_t)N * K;

    char* ws = (char*)d_ws;
    float* h1  = (float*)(ws);                          // N*H f32 (h1 / h3)
    float* h2  = (float*)(ws + (size_t)67108864);       // N*H f32 (h2 / h4)
    float* zE  = (float*)(ws + (size_t)134217728);      // N*L
    float* zq  = (float*)(ws + (size_t)150994944);      // N*L
    float* cn  = (float*)(ws + (size_t)167772160);      // K
    float* vqP = (float*)(ws + (size_t)167772160 + 16384);          // N
    float* sxP = (float*)(ws + (size_t)167772160 + 16384 + 65536);  // 1024

    dim3 blk(256);

    colnorm<<<K, 64, 0, stream>>>(pool, cn);

    // encoder
    gemm128<1, false><<<dim3(H / TS, N / TS), blk, 0, stream>>>(
        x, ew1, eb1, h1, N, D, H, nullptr, nullptr);
    gemm128<1, false><<<dim3(H / TS, N / TS), blk, 0, stream>>>(
        h1, ew2, eb2, h2, N, H, H, nullptr, nullptr);
    gemm128<0, false><<<dim3(L / TS, N / TS), blk, 0, stream>>>(
        h2, ew3, eb3, zE, N, H, L, nullptr, nullptr);

    // VQ scores: ||e_k||^2 - 2 z_e . e_k  -> z_discrete region
    gemm128<3, true><<<dim3(K / TS, N / TS), blk, 0, stream>>>(
        zE, pool, cn, zdisc, N, L, K, nullptr, nullptr);

    argmin_onehot<<<N, blk, 0, stream>>>(zdisc, zE, pool, zq, vqP);

    // decoder (STE: input is z_q)
    gemm128<1, false><<<dim3(H / TS, N / TS), blk, 0, stream>>>(
        zq, dw1, db1, h1, N, L, H, nullptr, nullptr);
    gemm128<1, false><<<dim3(H / TS, N / TS), blk, 0, stream>>>(
        h1, dw2, db2, h2, N, H, H, nullptr, nullptr);
    gemm128<2, false><<<dim3(D / TS, N / TS), blk, 0, stream>>>(
        h2, dw3, db3, xpred, N, H, D, x, sxP);

    loss_final<<<1, blk, 0, stream>>>(sxP, (D / TS) * (N / TS), vqP, N, lossp);
}

// Round 2
// 730.416 us; speedup vs baseline: 3.2360x; 3.2360x over previous
//
#include <hip/hip_runtime.h>
#include <math.h>

// MinVQVAE1D forward. Split-bf16 MFMA encoder+scores, plain bf16 MFMA decoder.
// N=16384, D=1024, H=1024, L=256, K=4096.
// out = [x_pred (N*D) f32 | z_discrete 0/1 f32 (N*K) | loss (1)]

#define MB (1024ULL * 1024ULL)

typedef __attribute__((ext_vector_type(8))) short s16x8;
typedef __attribute__((ext_vector_type(4))) float f32x4;

__device__ __forceinline__ ushort f2bf(float f) {
    unsigned u = __float_as_uint(f);
    u += 0x7fffu + ((u >> 16) & 1u);
    return (ushort)(u >> 16);
}
__device__ __forceinline__ float bf2f(ushort h) {
    return __uint_as_float(((unsigned)h) << 16);
}
__device__ __forceinline__ float gelu_f(float v) {
    return 0.5f * v * (1.0f + erff(v * 0.70710678118654752f));
}
__device__ __forceinline__ void gload16(const void* g, void* l) {
    __builtin_amdgcn_global_load_lds(
        (const __attribute__((address_space(1))) void*)g,
        (__attribute__((address_space(3))) void*)l, 16, 0, 0);
}

// ---------------------------------------------------------------------------
// f32 -> (hi, lo) bf16 split, elementwise (x, pool)
__global__ __launch_bounds__(256)
void split_conv(const float4* __restrict__ in, ushort4* __restrict__ oh,
                ushort4* __restrict__ ol, int n4)
{
    for (int i = blockIdx.x * 256 + threadIdx.x; i < n4; i += gridDim.x * 256) {
        float4 v = in[i];
        ushort4 h, l;
        h.x = f2bf(v.x); l.x = f2bf(v.x - bf2f(h.x));
        h.y = f2bf(v.y); l.y = f2bf(v.y - bf2f(h.y));
        h.z = f2bf(v.z); l.z = f2bf(v.z - bf2f(h.z));
        h.w = f2bf(v.w); l.w = f2bf(v.w - bf2f(h.w));
        oh[i] = h; ol[i] = l;
    }
}

// W [Kd, Nn] f32 -> WT hi/lo [Nn, Kd] bf16
__global__ __launch_bounds__(256)
void transpose_split(const float* __restrict__ in, ushort* __restrict__ oh,
                     ushort* __restrict__ ol, int Kd, int Nn)
{
    __shared__ float tile[32][33];
    const int n0 = blockIdx.x * 32, k0 = blockIdx.y * 32;
    const int tx = threadIdx.x & 31, ty = threadIdx.x >> 5;
    #pragma unroll
    for (int r = 0; r < 4; r++)
        tile[ty + r * 8][tx] = in[(size_t)(k0 + ty + r * 8) * Nn + n0 + tx];
    __syncthreads();
    #pragma unroll
    for (int r = 0; r < 4; r++) {
        float v = tile[tx][ty + r * 8];
        size_t o = (size_t)(n0 + ty + r * 8) * Kd + k0 + tx;
        ushort h = f2bf(v);
        oh[o] = h;
        ol[o] = f2bf(v - bf2f(h));
    }
}

// ||e_k||^2 per codebook row (L=256)
__global__ __launch_bounds__(64)
void colnorm(const float* __restrict__ pool, float* __restrict__ c)
{
    int r = blockIdx.x, lane = threadIdx.x;
    float4 v = *(const float4*)(pool + (size_t)r * 256 + lane * 4);
    float s = v.x * v.x + v.y * v.y + v.z * v.z + v.w * v.w;
    #pragma unroll
    for (int o = 32; o > 0; o >>= 1) s += __shfl_down(s, o);
    if (lane == 0) c[r] = s;
}

// ---------------------------------------------------------------------------
// MFMA GEMM: C[M,Nn] = A[M,Kd] @ B^T where B given as [Nn,Kd] (row-major).
// 128x128 tile, BK=64, 4 waves (2x2), 16x16x32 bf16 MFMA, XOR-swizzled LDS
// staged via global_load_lds (linear dest + pre-swizzled global source).
// EPI: 0=+bias (hi/lo out), 1=gelu(+bias) (hi[/lo] out),
//      2=sigmoid(+bias) f32 out + SSE vs xref, 3=VQ score argmin partials.
template<int EPI, bool SPLIT, bool WLO>
__global__ __launch_bounds__(256)
void gemm_mfma(const ushort* __restrict__ Ah, const ushort* __restrict__ Al,
               const ushort* __restrict__ Bh, const ushort* __restrict__ Bl,
               const float* __restrict__ bias, int Kd, int Nn,
               ushort* __restrict__ Ch, ushort* __restrict__ Cl,
               float* __restrict__ Cf, const float* __restrict__ xref,
               float* __restrict__ ssePartial,
               float* __restrict__ pval, int* __restrict__ pidx)
{
    extern __shared__ ushort smem[];
    ushort* AsH = smem;              // 128x64 bf16 = 16KB
    ushort* BsH = smem + 8192;
    ushort* AsL = SPLIT ? smem + 16384 : nullptr;
    ushort* BsL = SPLIT ? smem + 24576 : nullptr;

    const int tid = threadIdx.x;
    const int wave = tid >> 6, lane = tid & 63;
    const int m0 = blockIdx.y * 128, n0 = blockIdx.x * 128;
    const int wr = wave >> 1, wc = wave & 1;
    const int fcol = lane & 15, kgrp = lane >> 4;

    // staging: chunk = 1KB = 8 rows x 128B; per-lane source pre-swizzled
    const int srow = lane >> 3;                        // row within chunk
    const int scolb = (((lane & 7) ^ srow) << 4);      // swizzled col byte
    const size_t rowb = (size_t)Kd * 2;

    f32x4 acc[4][4];
    #pragma unroll
    for (int m = 0; m < 4; m++)
        #pragma unroll
        for (int n = 0; n < 4; n++)
            acc[m][n] = (f32x4){0.f, 0.f, 0.f, 0.f};

    // ds_read offsets (ushort units)
    int aoff[4], boff[4], koff[2];
    #pragma unroll
    for (int m = 0; m < 4; m++) aoff[m] = (wr * 64 + m * 16 + fcol) * 64;
    #pragma unroll
    for (int n = 0; n < 4; n++) boff[n] = (wc * 64 + n * 16 + fcol) * 64;
    #pragma unroll
    for (int ks = 0; ks < 2; ks++)
        koff[ks] = ((ks * 64 + kgrp * 16) ^ ((fcol & 7) << 4)) >> 1;

    const char* Ab = (const char*)Ah + (size_t)m0 * rowb;
    const char* Bb = (const char*)Bh + (size_t)n0 * rowb;
    const char* Abl = SPLIT ? (const char*)Al + (size_t)m0 * rowb : nullptr;
    const char* Bbl = SPLIT ? (const char*)Bl + (size_t)n0 * rowb : nullptr;

    for (int k0 = 0; k0 < Kd; k0 += 64) {
        #pragma unroll
        for (int pass = 0; pass < 4; pass++) {
            int chunk = wave * 4 + pass;
            size_t gb = (size_t)(chunk * 8 + srow) * rowb + (size_t)k0 * 2 + scolb;
            gload16(Ab + gb, AsH + chunk * 512);
            gload16(Bb + gb, BsH + chunk * 512);
            if (SPLIT) {
                gload16(Abl + gb, AsL + chunk * 512);
                gload16(Bbl + gb, BsL + chunk * 512);
            }
        }
        asm volatile("s_waitcnt vmcnt(0)" ::: "memory");
        __syncthreads();

        #pragma unroll
        for (int ks = 0; ks < 2; ks++) {
            s16x8 aH[4], bH[4];
            #pragma unroll
            for (int m = 0; m < 4; m++) aH[m] = *(const s16x8*)(AsH + aoff[m] + koff[ks]);
            #pragma unroll
            for (int n = 0; n < 4; n++) bH[n] = *(const s16x8*)(BsH + boff[n] + koff[ks]);
            if constexpr (SPLIT) {
                s16x8 aL[4], bL[4];
                #pragma unroll
                for (int m = 0; m < 4; m++) aL[m] = *(const s16x8*)(AsL + aoff[m] + koff[ks]);
                #pragma unroll
                for (int n = 0; n < 4; n++) bL[n] = *(const s16x8*)(BsL + boff[n] + koff[ks]);
                #pragma unroll
                for (int m = 0; m < 4; m++)
                    #pragma unroll
                    for (int n = 0; n < 4; n++) {
                        acc[m][n] = __builtin_amdgcn_mfma_f32_16x16x32_bf16(aH[m], bH[n], acc[m][n], 0, 0, 0);
                        acc[m][n] = __builtin_amdgcn_mfma_f32_16x16x32_bf16(aH[m], bL[n], acc[m][n], 0, 0, 0);
                        acc[m][n] = __builtin_amdgcn_mfma_f32_16x16x32_bf16(aL[m], bH[n], acc[m][n], 0, 0, 0);
                    }
            } else {
                #pragma unroll
                for (int m = 0; m < 4; m++)
                    #pragma unroll
                    for (int n = 0; n < 4; n++)
                        acc[m][n] = __builtin_amdgcn_mfma_f32_16x16x32_bf16(aH[m], bH[n], acc[m][n], 0, 0, 0);
            }
        }
        __syncthreads();
    }

    // ------------------------------ epilogue ------------------------------
    int colg[4];
    float bcol[4];
    #pragma unroll
    for (int n = 0; n < 4; n++) {
        colg[n] = n0 + wc * 64 + n * 16 + fcol;
        bcol[n] = bias[colg[n]];
    }

    if constexpr (EPI == 0 || EPI == 1) {
        #pragma unroll
        for (int m = 0; m < 4; m++)
            #pragma unroll
            for (int v = 0; v < 4; v++) {
                int row = m0 + wr * 64 + m * 16 + kgrp * 4 + v;
                size_t rb = (size_t)row * Nn;
                #pragma unroll
                for (int n = 0; n < 4; n++) {
                    float val = acc[m][n][v] + bcol[n];
                    if (EPI == 1) val = gelu_f(val);
                    ushort h = f2bf(val);
                    Ch[rb + colg[n]] = h;
                    if (WLO) Cl[rb + colg[n]] = f2bf(val - bf2f(h));
                }
            }
    } else if constexpr (EPI == 2) {
        float lsse = 0.0f;
        #pragma unroll
        for (int m = 0; m < 4; m++)
            #pragma unroll
            for (int v = 0; v < 4; v++) {
                int row = m0 + wr * 64 + m * 16 + kgrp * 4 + v;
                size_t rb = (size_t)row * Nn;
                #pragma unroll
                for (int n = 0; n < 4; n++) {
                    float val = acc[m][n][v] + bcol[n];
                    val = 1.0f / (1.0f + expf(-val));
                    Cf[rb + colg[n]] = val;
                    float d = xref[rb + colg[n]] - val;
                    lsse += d * d;
                }
            }
        __syncthreads();
        float* red = (float*)smem;
        red[tid] = lsse;
        __syncthreads();
        for (int s = 128; s > 0; s >>= 1) {
            if (tid < s) red[tid] += red[tid + s];
            __syncthreads();
        }
        if (tid == 0) ssePartial[blockIdx.y * gridDim.x + blockIdx.x] = red[0];
    } else if constexpr (EPI == 3) {
        __syncthreads();                     // done with tiles; reuse smem
        float* sv = (float*)smem;            // [2][128]
        int*   si = (int*)(sv + 256);
        #pragma unroll
        for (int m = 0; m < 4; m++)
            #pragma unroll
            for (int v = 0; v < 4; v++) {
                float best = INFINITY;
                int bidx = 0x7fffffff;
                #pragma unroll
                for (int n = 0; n < 4; n++) {
                    float sc = bcol[n] - 2.0f * acc[m][n][v];
                    if (sc < best || (sc == best && colg[n] < bidx)) { best = sc; bidx = colg[n]; }
                }
                #pragma unroll
                for (int d = 1; d < 16; d <<= 1) {
                    float ov = __shfl_xor(best, d, 64);
                    int   oi = __shfl_xor(bidx, d, 64);
                    if (ov < best || (ov == best && oi < bidx)) { best = ov; bidx = oi; }
                }
                if (fcol == 0) {
                    int rl = wr * 64 + m * 16 + kgrp * 4 + v;
                    sv[wc * 128 + rl] = best;
                    si[wc * 128 + rl] = bidx;
                }
            }
        __syncthreads();
        if (tid < 128) {
            float v0 = sv[tid], v1 = sv[128 + tid];
            int   i0 = si[tid], i1 = si[128 + tid];
            if (v1 < v0 || (v1 == v0 && i1 < i0)) { v0 = v1; i0 = i1; }
            pval[(size_t)(m0 + tid) * gridDim.x + blockIdx.x] = v0;
            pidx[(size_t)(m0 + tid) * gridDim.x + blockIdx.x] = i0;
        }
    }
}

// ---------------------------------------------------------------------------
// Per-row: reduce 32 block partials -> kbest; write one-hot row; gather z_q;
// VQ loss partial.
__global__ __launch_bounds__(256)
void argmin_final(const float* __restrict__ pval, const int* __restrict__ pidx,
                  int nblk,
                  const ushort* __restrict__ zeh, const ushort* __restrict__ zel,
                  const float* __restrict__ pool,
                  float* __restrict__ zdisc, ushort* __restrict__ zqh,
                  float* __restrict__ vqP)
{
    const int r = blockIdx.x, t = threadIdx.x;
    __shared__ int kb;
    __shared__ float red[256];
    if (t == 0) {
        float best = pval[(size_t)r * nblk];
        int bi = pidx[(size_t)r * nblk];
        for (int c = 1; c < nblk; c++) {
            float v = pval[(size_t)r * nblk + c];
            int i = pidx[(size_t)r * nblk + c];
            if (v < best || (v == best && i < bi)) { best = v; bi = i; }
        }
        kb = bi;
    }
    __syncthreads();
    const int kbest = kb;

    float4* zrow = (float4*)(zdisc + (size_t)r * 4096);
    for (int j = t; j < 1024; j += 256) {
        float4 o = {0.f, 0.f, 0.f, 0.f};
        if ((kbest >> 2) == j) ((float*)&o)[kbest & 3] = 1.0f;
        zrow[j] = o;
    }

    float zq = pool[(size_t)kbest * 256 + t];
    zqh[(size_t)r * 256 + t] = f2bf(zq);
    float ze = bf2f(zeh[(size_t)r * 256 + t]) + bf2f(zel[(size_t)r * 256 + t]);
    float d = ze - zq;
    red[t] = d * d;
    __syncthreads();
    for (int s = 128; s > 0; s >>= 1) {
        if (t < s) red[t] += red[t + s];
        __syncthreads();
    }
    if (t == 0) vqP[r] = red[0];
}

__global__ __launch_bounds__(256)
void loss_final(const float* __restrict__ sseP, int nP,
                const float* __restrict__ vqP, int nV,
                float* __restrict__ out)
{
    int tid = threadIdx.x;
    float sx = 0.0f, svq = 0.0f;
    for (int i = tid; i < nP; i += 256) sx += sseP[i];
    for (int i = tid; i < nV; i += 256) svq += vqP[i];
    __shared__ float a[256], b[256];
    a[tid] = sx; b[tid] = svq;
    __syncthreads();
    for (int s = 128; s > 0; s >>= 1) {
        if (tid < s) { a[tid] += a[tid + s]; b[tid] += b[tid + s]; }
        __syncthreads();
    }
    if (tid == 0) out[0] = (a[0] + 1.25f * b[0]) / 16384.0f;
}

// ---------------------------------------------------------------------------
extern "C" void kernel_launch(void* const* d_in, const int* in_sizes, int n_in,
                              void* d_out, int out_size, void* d_ws, size_t ws_size,
                              hipStream_t stream)
{
    const float* x    = (const float*)d_in[0];
    const float* pool = (const float*)d_in[1];
    const float* ew1  = (const float*)d_in[2];
    const float* eb1  = (const float*)d_in[3];
    const float* ew2  = (const float*)d_in[4];
    const float* eb2  = (const float*)d_in[5];
    const float* ew3  = (const float*)d_in[6];
    const float* eb3  = (const float*)d_in[7];
    const float* dw1  = (const float*)d_in[8];
    const float* db1  = (const float*)d_in[9];
    const float* dw2  = (const float*)d_in[10];
    const float* db2  = (const float*)d_in[11];
    const float* dw3  = (const float*)d_in[12];
    const float* db3  = (const float*)d_in[13];

    const int N = 16384, D = 1024, H = 1024, L = 256, K = 4096;

    float* out   = (float*)d_out;
    float* xpred = out;
    float* zdisc = out + (size_t)N * D;
    float* lossp = zdisc + (size_t)N * K;

    char* ws = (char*)d_ws;
    // x hi/lo live only through enc1; ze/zq reuse this region afterwards.
    ushort* xh  = (ushort*)(ws + 0 * MB);     // 32MB
    ushort* xl  = (ushort*)(ws + 32 * MB);    // 32MB
    ushort* zeh = (ushort*)(ws + 0 * MB);     // 8MB (after enc1/enc2)
    ushort* zel = (ushort*)(ws + 8 * MB);     // 8MB
    ushort* zqh = (ushort*)(ws + 16 * MB);    // 8MB
    ushort* h1h = (ushort*)(ws + 64 * MB);    // 32MB (enc h1, later dec h3)
    ushort* h1l = (ushort*)(ws + 96 * MB);    // 32MB
    ushort* h2h = (ushort*)(ws + 128 * MB);   // 32MB (enc h2, later dec h4)
    ushort* h2l = (ushort*)(ws + 160 * MB);   // 32MB
    ushort* poolh = (ushort*)(ws + 192 * MB); // 2MB
    ushort* pooll = (ushort*)(ws + 194 * MB); // 2MB
    ushort* w1h = (ushort*)(ws + 196 * MB);   // ew1T 2MB
    ushort* w1l = (ushort*)(ws + 198 * MB);
    ushort* w2h = (ushort*)(ws + 200 * MB);   // ew2T
    ushort* w2l = (ushort*)(ws + 202 * MB);
    ushort* w3h = (ushort*)(ws + 204 * MB);                    // ew3T 0.5MB
    ushort* w3l = (ushort*)(ws + 204 * MB + 512 * 1024);
    ushort* v1h = (ushort*)(ws + 205 * MB);                    // dw1T 0.5MB
    ushort* v1l = (ushort*)(ws + 205 * MB + 512 * 1024);
    ushort* v2h = (ushort*)(ws + 206 * MB);   // dw2T
    ushort* v2l = (ushort*)(ws + 208 * MB);
    ushort* v3h = (ushort*)(ws + 210 * MB);   // dw3T
    ushort* v3l = (ushort*)(ws + 212 * MB);
    float*  cn  = (float*)(ws + 214 * MB);    // 16KB
    float*  pv  = (float*)(ws + 215 * MB);    // 2MB
    int*    pi  = (int*)(ws + 217 * MB);      // 2MB
    float*  vqP = (float*)(ws + 219 * MB);    // 64KB
    float*  sxP = (float*)(ws + 220 * MB);    // 4KB

    const size_t shSplit = 64 * 1024, shPlain = 32 * 1024;
    dim3 blk(256);

    // prep
    split_conv<<<2048, blk, 0, stream>>>((const float4*)x, (ushort4*)xh, (ushort4*)xl, N * D / 4);
    split_conv<<<512, blk, 0, stream>>>((const float4*)pool, (ushort4*)poolh, (ushort4*)pooll, K * L / 4);
    colnorm<<<K, 64, 0, stream>>>(pool, cn);
    transpose_split<<<dim3(H / 32, D / 32), blk, 0, stream>>>(ew1, w1h, w1l, D, H);
    transpose_split<<<dim3(H / 32, H / 32), blk, 0, stream>>>(ew2, w2h, w2l, H, H);
    transpose_split<<<dim3(L / 32, H / 32), blk, 0, stream>>>(ew3, w3h, w3l, H, L);
    transpose_split<<<dim3(H / 32, L / 32), blk, 0, stream>>>(dw1, v1h, v1l, L, H);
    transpose_split<<<dim3(H / 32, H / 32), blk, 0, stream>>>(dw2, v2h, v2l, H, H);
    transpose_split<<<dim3(D / 32, H / 32), blk, 0, stream>>>(dw3, v3h, v3l, H, D);

    // encoder (split)
    gemm_mfma<1, true, true><<<dim3(H / 128, N / 128), blk, shSplit, stream>>>(
        xh, xl, w1h, w1l, eb1, D, H, h1h, h1l, nullptr, nullptr, nullptr, nullptr, nullptr);
    gemm_mfma<1, true, true><<<dim3(H / 128, N / 128), blk, shSplit, stream>>>(
        h1h, h1l, w2h, w2l, eb2, H, H, h2h, h2l, nullptr, nullptr, nullptr, nullptr, nullptr);
    gemm_mfma<0, true, true><<<dim3(L / 128, N / 128), blk, shSplit, stream>>>(
        h2h, h2l, w3h, w3l, eb3, H, L, zeh, zel, nullptr, nullptr, nullptr, nullptr, nullptr);

    // VQ scores + fused per-block argmin (split)
    gemm_mfma<3, true, false><<<dim3(K / 128, N / 128), blk, shSplit, stream>>>(
        zeh, zel, poolh, pooll, cn, L, K, nullptr, nullptr, nullptr, nullptr, nullptr, pv, pi);

    argmin_final<<<N, blk, 0, stream>>>(pv, pi, K / 128, zeh, zel, pool, zdisc, zqh, vqP);

    // decoder (plain bf16)
    gemm_mfma<1, false, false><<<dim3(H / 128, N / 128), blk, shPlain, stream>>>(
        zqh, nullptr, v1h, nullptr, db1, L, H, h1h, nullptr, nullptr, nullptr, nullptr, nullptr, nullptr);
    gemm_mfma<1, false, false><<<dim3(H / 128, N / 128), blk, shPlain, stream>>>(
        h1h, nullptr, v2h, nullptr, db2, H, H, h2h, nullptr, nullptr, nullptr, nullptr, nullptr, nullptr);
    gemm_mfma<2, false, false><<<dim3(D / 128, N / 128), blk, shPlain, stream>>>(
        h2h, nullptr, v3h, nullptr, db3, H, D, nullptr, nullptr, xpred, x, sxP, nullptr, nullptr);

    loss_final<<<1, blk, 0, stream>>>(sxP, (D / 128) * (N / 128), vqP, N, lossp);
}

// Round 3
// 723.182 us; speedup vs baseline: 3.2683x; 1.0100x over previous
//
#include <hip/hip_runtime.h>
#include <math.h>

// MinVQVAE1D forward. Pipelined (3-buffer, counted-vmcnt) MFMA GEMMs.
// Split-bf16 (hi/lo) encoder+scores, plain bf16 decoder.
// N=16384, D=1024, H=1024, L=256, K=4096.
// out = [x_pred (N*D) f32 | z_discrete 0/1 f32 (N*K) | loss (1)]

#define MB (1024ULL * 1024ULL)

typedef __attribute__((ext_vector_type(8))) short s16x8;
typedef __attribute__((ext_vector_type(4))) float f32x4;

__device__ __forceinline__ ushort f2bf(float f) {
    unsigned u = __float_as_uint(f);
    u += 0x7fffu + ((u >> 16) & 1u);
    return (ushort)(u >> 16);
}
__device__ __forceinline__ float bf2f(ushort h) {
    return __uint_as_float(((unsigned)h) << 16);
}
__device__ __forceinline__ float gelu_f(float v) {
    return 0.5f * v * (1.0f + erff(v * 0.70710678118654752f));
}
__device__ __forceinline__ void gload16(const void* g, void* l) {
    __builtin_amdgcn_global_load_lds(
        (const __attribute__((address_space(1))) void*)g,
        (__attribute__((address_space(3))) void*)l, 16, 0, 0);
}

// ---------------------------------------------------------------------------
// f32 [R][K] -> hilo-packed bf16: row stride 2K ushorts, per 32-k slab:
// [32 hi | 32 lo]. Each thread handles 8 consecutive elements (8-aligned).
__global__ __launch_bounds__(256)
void split_pack(const float* __restrict__ in, ushort* __restrict__ out,
                int R, int K)
{
    const int nch = R * (K >> 3);
    for (int i = blockIdx.x * 256 + threadIdx.x; i < nch; i += gridDim.x * 256) {
        const int row = i / (K >> 3);
        const int k8 = (i - row * (K >> 3)) * 8;
        const float4 v0 = *(const float4*)(in + (size_t)row * K + k8);
        const float4 v1 = *(const float4*)(in + (size_t)row * K + k8 + 4);
        float f[8] = {v0.x, v0.y, v0.z, v0.w, v1.x, v1.y, v1.z, v1.w};
        ushort h[8], l[8];
        #pragma unroll
        for (int j = 0; j < 8; j++) {
            h[j] = f2bf(f[j]);
            l[j] = f2bf(f[j] - bf2f(h[j]));
        }
        size_t o = (size_t)row * 2 * K + ((k8 >> 5) << 6) + (k8 & 31);
        *(ushort4*)(out + o)      = make_ushort4(h[0], h[1], h[2], h[3]);
        *(ushort4*)(out + o + 4)  = make_ushort4(h[4], h[5], h[6], h[7]);
        *(ushort4*)(out + o + 32) = make_ushort4(l[0], l[1], l[2], l[3]);
        *(ushort4*)(out + o + 36) = make_ushort4(l[4], l[5], l[6], l[7]);
    }
}

// W [Kd, Nn] f32 -> out [Nn][Kd]; PACK -> hilo-packed, else plain bf16.
template<bool PACK>
__global__ __launch_bounds__(256)
void transpose_cvt(const float* __restrict__ in, ushort* __restrict__ out,
                   int Kd, int Nn)
{
    __shared__ float tile[32][33];
    const int n0 = blockIdx.x * 32, k0 = blockIdx.y * 32;
    const int tx = threadIdx.x & 31, ty = threadIdx.x >> 5;
    #pragma unroll
    for (int r = 0; r < 4; r++)
        tile[ty + r * 8][tx] = in[(size_t)(k0 + ty + r * 8) * Nn + n0 + tx];
    __syncthreads();
    #pragma unroll
    for (int r = 0; r < 4; r++) {
        const float v = tile[tx][ty + r * 8];
        const int row = n0 + ty + r * 8, k = k0 + tx;
        if constexpr (PACK) {
            size_t o = (size_t)row * 2 * Kd + ((k >> 5) << 6) + (k & 31);
            ushort h = f2bf(v);
            out[o] = h;
            out[o + 32] = f2bf(v - bf2f(h));
        } else {
            out[(size_t)row * Kd + k] = f2bf(v);
        }
    }
}

// ||e_k||^2 per codebook row (L=256)
__global__ __launch_bounds__(64)
void colnorm(const float* __restrict__ pool, float* __restrict__ c)
{
    int r = blockIdx.x, lane = threadIdx.x;
    float4 v = *(const float4*)(pool + (size_t)r * 256 + lane * 4);
    float s = v.x * v.x + v.y * v.y + v.z * v.z + v.w * v.w;
    #pragma unroll
    for (int o = 32; o > 0; o >>= 1) s += __shfl_down(s, o);
    if (lane == 0) c[r] = s;
}

// ---------------------------------------------------------------------------
// Pipelined MFMA GEMM: C[M,Nn] = A[M,Kd] @ B^T, B given as [Nn,Kd].
// Tile 256x128, 512 threads (8 waves = 4x2), per-wave 64x64 output.
// 3 LDS buffers x 48KB (A 256 rows + B 128 rows, 128B/row K-slab), distance-2
// prefetch, counted s_waitcnt vmcnt(6) + RAW s_barrier (no syncthreads drain).
// SPLIT: BK=32, rows = [32 hi | 32 lo]; plain: BK=64.
// EPI: 0=+bias, 1=gelu(+bias), 2=sigmoid(+bias)+SSE, 3=VQ argmin partials.
template<int EPI, bool SPLIT, bool PACKOUT>
__global__ __launch_bounds__(512, 2)
void gemm_pipe(const ushort* __restrict__ A, const ushort* __restrict__ B,
               const float* __restrict__ bias, int Kd, int Nn,
               int rsA, int rsB,                    // row strides in BYTES
               ushort* __restrict__ Cu, float* __restrict__ Cf,
               const float* __restrict__ xref, float* __restrict__ ssePartial,
               float* __restrict__ pval, int* __restrict__ pidx)
{
    extern __shared__ ushort smem[];                // 3 x 24576 ushorts
    const int tid = threadIdx.x;
    const int wave = tid >> 6, lane = tid & 63;
    const int m0 = blockIdx.y * 256, n0 = blockIdx.x * 128;
    const int wr = wave >> 1, wc = wave & 1;
    const int fcol = lane & 15, kgrp = lane >> 4;
    const int NT = Kd / (SPLIT ? 32 : 64);

    const int srow = lane >> 3;                     // row within 8-row chunk
    const int sswz = ((lane & 7) ^ srow) << 4;      // swizzled src byte
    const char* Abase = (const char*)A + (size_t)m0 * rsA;
    const char* Bbase = (const char*)B + (size_t)n0 * rsB;

    f32x4 acc[4][4];
    #pragma unroll
    for (int m = 0; m < 4; m++)
        #pragma unroll
        for (int n = 0; n < 4; n++)
            acc[m][n] = (f32x4){0.f, 0.f, 0.f, 0.f};

    auto STAGE = [&](int buf, int t) {
        ushort* dst = smem + buf * 24576;
        const size_t kb = (size_t)t * 128;
        #pragma unroll
        for (int g = 0; g < 4; g++) {
            const int rb = g * 64 + wave * 8;
            gload16(Abase + (size_t)(rb + srow) * rsA + kb + sswz, dst + rb * 64);
        }
        #pragma unroll
        for (int g = 0; g < 2; g++) {
            const int rb = g * 64 + wave * 8;
            gload16(Bbase + (size_t)(rb + srow) * rsB + kb + sswz,
                    dst + (256 + rb) * 64);
        }
    };
    auto LD = [&](int buf, int r, int u) -> s16x8 {
        return *(const s16x8*)(smem + buf * 24576 + r * 64 + ((u ^ (r & 7)) << 3));
    };

    STAGE(0, 0);
    STAGE(1, 1);
    for (int t = 0; t < NT; ++t) {
        if (t + 1 < NT) asm volatile("s_waitcnt vmcnt(6)" ::: "memory");
        else            asm volatile("s_waitcnt vmcnt(0)" ::: "memory");
        __builtin_amdgcn_s_barrier();
        if (t + 2 < NT) STAGE((t + 2) % 3, t + 2);
        const int buf = t % 3;
        if constexpr (SPLIT) {
            s16x8 aH[4], aL[4], bH[4], bL[4];
            #pragma unroll
            for (int m = 0; m < 4; m++) {
                const int r = wr * 64 + m * 16 + fcol;
                aH[m] = LD(buf, r, kgrp);
                aL[m] = LD(buf, r, 4 + kgrp);
            }
            #pragma unroll
            for (int n = 0; n < 4; n++) {
                const int r = 256 + wc * 64 + n * 16 + fcol;
                bH[n] = LD(buf, r, kgrp);
                bL[n] = LD(buf, r, 4 + kgrp);
            }
            #pragma unroll
            for (int m = 0; m < 4; m++)
                #pragma unroll
                for (int n = 0; n < 4; n++) {
                    acc[m][n] = __builtin_amdgcn_mfma_f32_16x16x32_bf16(aH[m], bH[n], acc[m][n], 0, 0, 0);
                    acc[m][n] = __builtin_amdgcn_mfma_f32_16x16x32_bf16(aH[m], bL[n], acc[m][n], 0, 0, 0);
                    acc[m][n] = __builtin_amdgcn_mfma_f32_16x16x32_bf16(aL[m], bH[n], acc[m][n], 0, 0, 0);
                }
        } else {
            #pragma unroll
            for (int ks = 0; ks < 2; ks++) {
                s16x8 a[4], b[4];
                #pragma unroll
                for (int m = 0; m < 4; m++)
                    a[m] = LD(buf, wr * 64 + m * 16 + fcol, ks * 4 + kgrp);
                #pragma unroll
                for (int n = 0; n < 4; n++)
                    b[n] = LD(buf, 256 + wc * 64 + n * 16 + fcol, ks * 4 + kgrp);
                #pragma unroll
                for (int m = 0; m < 4; m++)
                    #pragma unroll
                    for (int n = 0; n < 4; n++)
                        acc[m][n] = __builtin_amdgcn_mfma_f32_16x16x32_bf16(a[m], b[n], acc[m][n], 0, 0, 0);
            }
        }
    }
    __builtin_amdgcn_sched_barrier(0);

    // ------------------------------ epilogue ------------------------------
    int colg[4];
    float bcol[4];
    #pragma unroll
    for (int n = 0; n < 4; n++) {
        colg[n] = n0 + wc * 64 + n * 16 + fcol;
        bcol[n] = bias[colg[n]];
    }

    if constexpr (EPI == 0 || EPI == 1) {
        #pragma unroll
        for (int m = 0; m < 4; m++)
            #pragma unroll
            for (int v = 0; v < 4; v++) {
                const int row = m0 + wr * 64 + m * 16 + kgrp * 4 + v;
                #pragma unroll
                for (int n = 0; n < 4; n++) {
                    float val = acc[m][n][v] + bcol[n];
                    if (EPI == 1) val = gelu_f(val);
                    if constexpr (PACKOUT) {
                        size_t o = (size_t)row * 2 * Nn + ((colg[n] >> 5) << 6) + (colg[n] & 31);
                        ushort h = f2bf(val);
                        Cu[o] = h;
                        Cu[o + 32] = f2bf(val - bf2f(h));
                    } else {
                        Cu[(size_t)row * Nn + colg[n]] = f2bf(val);
                    }
                }
            }
    } else if constexpr (EPI == 2) {
        float lsse = 0.0f;
        #pragma unroll
        for (int m = 0; m < 4; m++)
            #pragma unroll
            for (int v = 0; v < 4; v++) {
                const int row = m0 + wr * 64 + m * 16 + kgrp * 4 + v;
                const size_t rb = (size_t)row * Nn;
                #pragma unroll
                for (int n = 0; n < 4; n++) {
                    float val = acc[m][n][v] + bcol[n];
                    val = 1.0f / (1.0f + expf(-val));
                    Cf[rb + colg[n]] = val;
                    float d = xref[rb + colg[n]] - val;
                    lsse += d * d;
                }
            }
        __syncthreads();
        float* red = (float*)smem;
        red[tid] = lsse;
        __syncthreads();
        for (int s = 256; s > 0; s >>= 1) {
            if (tid < s) red[tid] += red[tid + s];
            __syncthreads();
        }
        if (tid == 0) ssePartial[blockIdx.y * gridDim.x + blockIdx.x] = red[0];
    } else if constexpr (EPI == 3) {
        __syncthreads();
        float* sv = (float*)smem;            // [2][256]
        int*   si = (int*)(sv + 512);
        #pragma unroll
        for (int m = 0; m < 4; m++)
            #pragma unroll
            for (int v = 0; v < 4; v++) {
                float best = INFINITY;
                int bidx = 0x7fffffff;
                #pragma unroll
                for (int n = 0; n < 4; n++) {
                    float sc = bcol[n] - 2.0f * acc[m][n][v];
                    if (sc < best || (sc == best && colg[n] < bidx)) { best = sc; bidx = colg[n]; }
                }
                #pragma unroll
                for (int d = 1; d < 16; d <<= 1) {
                    float ov = __shfl_xor(best, d, 64);
                    int   oi = __shfl_xor(bidx, d, 64);
                    if (ov < best || (ov == best && oi < bidx)) { best = ov; bidx = oi; }
                }
                if (fcol == 0) {
                    const int rl = wr * 64 + m * 16 + kgrp * 4 + v;
                    sv[wc * 256 + rl] = best;
                    si[wc * 256 + rl] = bidx;
                }
            }
        __syncthreads();
        if (tid < 256) {
            float v0 = sv[tid], v1 = sv[256 + tid];
            int   i0 = si[tid], i1 = si[256 + tid];
            if (v1 < v0 || (v1 == v0 && i1 < i0)) { v0 = v1; i0 = i1; }
            pval[(size_t)(m0 + tid) * gridDim.x + blockIdx.x] = v0;
            pidx[(size_t)(m0 + tid) * gridDim.x + blockIdx.x] = i0;
        }
    }
}

// ---------------------------------------------------------------------------
// Per-row: reduce 32 block partials -> kbest; one-hot; gather z_q; VQ partial.
__global__ __launch_bounds__(256)
void argmin_final(const float* __restrict__ pval, const int* __restrict__ pidx,
                  int nblk, const ushort* __restrict__ zEp,
                  const float* __restrict__ pool,
                  float* __restrict__ zdisc, ushort* __restrict__ zq,
                  float* __restrict__ vqP)
{
    const int r = blockIdx.x, t = threadIdx.x;
    __shared__ int kb;
    __shared__ float red[256];
    if (t == 0) {
        float best = pval[(size_t)r * nblk];
        int bi = pidx[(size_t)r * nblk];
        for (int c = 1; c < nblk; c++) {
            float v = pval[(size_t)r * nblk + c];
            int i = pidx[(size_t)r * nblk + c];
            if (v < best || (v == best && i < bi)) { best = v; bi = i; }
        }
        kb = bi;
    }
    __syncthreads();
    const int kbest = kb;

    float4* zrow = (float4*)(zdisc + (size_t)r * 4096);
    for (int j = t; j < 1024; j += 256) {
        float4 o = {0.f, 0.f, 0.f, 0.f};
        if ((kbest >> 2) == j) ((float*)&o)[kbest & 3] = 1.0f;
        zrow[j] = o;
    }

    float zqv = pool[(size_t)kbest * 256 + t];
    zq[(size_t)r * 256 + t] = f2bf(zqv);
    size_t zo = (size_t)r * 512 + ((t >> 5) << 6) + (t & 31);
    float ze = bf2f(zEp[zo]) + bf2f(zEp[zo + 32]);
    float d = ze - zqv;
    red[t] = d * d;
    __syncthreads();
    for (int s = 128; s > 0; s >>= 1) {
        if (t < s) red[t] += red[t + s];
        __syncthreads();
    }
    if (t == 0) vqP[r] = red[0];
}

__global__ __launch_bounds__(256)
void loss_final(const float* __restrict__ sseP, int nP,
                const float* __restrict__ vqP, int nV,
                float* __restrict__ out)
{
    int tid = threadIdx.x;
    float sx = 0.0f, svq = 0.0f;
    for (int i = tid; i < nP; i += 256) sx += sseP[i];
    for (int i = tid; i < nV; i += 256) svq += vqP[i];
    __shared__ float a[256], b[256];
    a[tid] = sx; b[tid] = svq;
    __syncthreads();
    for (int s = 128; s > 0; s >>= 1) {
        if (tid < s) { a[tid] += a[tid + s]; b[tid] += b[tid + s]; }
        __syncthreads();
    }
    if (tid == 0) out[0] = (a[0] + 1.25f * b[0]) / 16384.0f;
}

// ---------------------------------------------------------------------------
extern "C" void kernel_launch(void* const* d_in, const int* in_sizes, int n_in,
                              void* d_out, int out_size, void* d_ws, size_t ws_size,
                              hipStream_t stream)
{
    const float* x    = (const float*)d_in[0];
    const float* pool = (const float*)d_in[1];
    const float* ew1  = (const float*)d_in[2];
    const float* eb1  = (const float*)d_in[3];
    const float* ew2  = (const float*)d_in[4];
    const float* eb2  = (const float*)d_in[5];
    const float* ew3  = (const float*)d_in[6];
    const float* eb3  = (const float*)d_in[7];
    const float* dw1  = (const float*)d_in[8];
    const float* db1  = (const float*)d_in[9];
    const float* dw2  = (const float*)d_in[10];
    const float* db2  = (const float*)d_in[11];
    const float* dw3  = (const float*)d_in[12];
    const float* db3  = (const float*)d_in[13];

    const int N = 16384, D = 1024, H = 1024, L = 256, K = 4096;

    float* out   = (float*)d_out;
    float* xpred = out;
    float* zdisc = out + (size_t)N * D;
    float* lossp = zdisc + (size_t)N * K;

    char* ws = (char*)d_ws;
    ushort* xp    = (ushort*)(ws + 0 * MB);    // 64MB packed x
    ushort* h1p   = (ushort*)(ws + 64 * MB);   // 64MB
    ushort* h2p   = (ushort*)(ws + 128 * MB);  // 64MB
    ushort* zEp   = (ushort*)(ws + 192 * MB);  // 16MB
    ushort* zq    = (ushort*)(ws + 208 * MB);  // 8MB plain bf16
    ushort* poolp = (ushort*)(ws + 216 * MB);  // 4MB
    ushort* w1p   = (ushort*)(ws + 220 * MB);  // 4MB
    ushort* w2p   = (ushort*)(ws + 224 * MB);  // 4MB
    ushort* w3p   = (ushort*)(ws + 228 * MB);  // 1MB
    ushort* v1    = (ushort*)(ws + 229 * MB);  // 0.5MB plain
    ushort* v2    = (ushort*)(ws + 230 * MB);  // 2MB
    ushort* v3    = (ushort*)(ws + 232 * MB);  // 2MB
    ushort* h3    = (ushort*)(ws + 240 * MB);  // 32MB plain
    ushort* h4    = (ushort*)(ws + 272 * MB);  // 32MB
    float*  cn    = (float*)(ws + 304 * MB);   // 16KB
    float*  pv    = (float*)(ws + 305 * MB);   // 2MB
    int*    pi    = (int*)(ws + 307 * MB);     // 2MB
    float*  vqP   = (float*)(ws + 309 * MB);   // 64KB
    float*  sxP   = (float*)(ws + 310 * MB);   // 2KB

    const int SH = 3 * 24576 * 2;              // 147456 B dynamic LDS
    (void)hipFuncSetAttribute((const void*)gemm_pipe<1, true, true>,
        hipFuncAttributeMaxDynamicSharedMemorySize, SH);
    (void)hipFuncSetAttribute((const void*)gemm_pipe<0, true, true>,
        hipFuncAttributeMaxDynamicSharedMemorySize, SH);
    (void)hipFuncSetAttribute((const void*)gemm_pipe<3, true, false>,
        hipFuncAttributeMaxDynamicSharedMemorySize, SH);
    (void)hipFuncSetAttribute((const void*)gemm_pipe<1, false, false>,
        hipFuncAttributeMaxDynamicSharedMemorySize, SH);
    (void)hipFuncSetAttribute((const void*)gemm_pipe<2, false, false>,
        hipFuncAttributeMaxDynamicSharedMemorySize, SH);

    dim3 blk(256), gblk(512);

    // prep
    split_pack<<<2048, blk, 0, stream>>>(x, xp, N, D);
    split_pack<<<512, blk, 0, stream>>>(pool, poolp, K, L);
    colnorm<<<K, 64, 0, stream>>>(pool, cn);
    transpose_cvt<true><<<dim3(H / 32, D / 32), blk, 0, stream>>>(ew1, w1p, D, H);
    transpose_cvt<true><<<dim3(H / 32, H / 32), blk, 0, stream>>>(ew2, w2p, H, H);
    transpose_cvt<true><<<dim3(L / 32, H / 32), blk, 0, stream>>>(ew3, w3p, H, L);
    transpose_cvt<false><<<dim3(H / 32, L / 32), blk, 0, stream>>>(dw1, v1, L, H);
    transpose_cvt<false><<<dim3(H / 32, H / 32), blk, 0, stream>>>(dw2, v2, H, H);
    transpose_cvt<false><<<dim3(D / 32, H / 32), blk, 0, stream>>>(dw3, v3, H, D);

    // encoder (split, packed in/out)
    gemm_pipe<1, true, true><<<dim3(H / 128, N / 256), gblk, SH, stream>>>(
        xp, w1p, eb1, D, H, 2 * D * 2, 2 * D * 2, h1p, nullptr, nullptr, nullptr, nullptr, nullptr);
    gemm_pipe<1, true, true><<<dim3(H / 128, N / 256), gblk, SH, stream>>>(
        h1p, w2p, eb2, H, H, 2 * H * 2, 2 * H * 2, h2p, nullptr, nullptr, nullptr, nullptr, nullptr);
    gemm_pipe<0, true, true><<<dim3(L / 128, N / 256), gblk, SH, stream>>>(
        h2p, w3p, eb3, H, L, 2 * H * 2, 2 * H * 2, zEp, nullptr, nullptr, nullptr, nullptr, nullptr);

    // VQ scores + fused per-block argmin (split)
    gemm_pipe<3, true, false><<<dim3(K / 128, N / 256), gblk, SH, stream>>>(
        zEp, poolp, cn, L, K, 2 * L * 2, 2 * L * 2, nullptr, nullptr, nullptr, nullptr, pv, pi);

    argmin_final<<<N, blk, 0, stream>>>(pv, pi, K / 128, zEp, pool, zdisc, zq, vqP);

    // decoder (plain bf16)
    gemm_pipe<1, false, false><<<dim3(H / 128, N / 256), gblk, SH, stream>>>(
        zq, v1, db1, L, H, L * 2, L * 2, h3, nullptr, nullptr, nullptr, nullptr, nullptr);
    gemm_pipe<1, false, false><<<dim3(H / 128, N / 256), gblk, SH, stream>>>(
        h3, v2, db2, H, H, H * 2, H * 2, h4, nullptr, nullptr, nullptr, nullptr, nullptr);
    gemm_pipe<2, false, false><<<dim3(D / 128, N / 256), gblk, SH, stream>>>(
        h4, v3, db3, H, D, H * 2, H * 2, nullptr, xpred, x, sxP, nullptr, nullptr);

    loss_final<<<1, blk, 0, stream>>>(sxP, (D / 128) * (N / 256), vqP, N, lossp);
}

// Round 5
// 643.983 us; speedup vs baseline: 3.6703x; 1.1230x over previous
//
#include <hip/hip_runtime.h>
#include <math.h>

// MinVQVAE1D forward. Pipelined (3-buffer, counted-vmcnt) MFMA GEMMs with
// XCD-swizzle + setprio. Split-bf16 (hi/lo) encoder+scores, plain bf16 decoder.
// N=16384, D=1024, H=1024, L=256, K=4096.
// out = [x_pred (N*D) f32 | z_discrete 0/1 f32 (N*K) | loss (1)]

#define MB (1024ULL * 1024ULL)

typedef __attribute__((ext_vector_type(8))) short s16x8;
typedef __attribute__((ext_vector_type(4))) float f32x4;

__device__ __forceinline__ ushort f2bf(float f) {
    unsigned u = __float_as_uint(f);
    u += 0x7fffu + ((u >> 16) & 1u);
    return (ushort)(u >> 16);
}
__device__ __forceinline__ float bf2f(ushort h) {
    return __uint_as_float(((unsigned)h) << 16);
}
__device__ __forceinline__ float gelu_f(float v) {
    return 0.5f * v * (1.0f + erff(v * 0.70710678118654752f));
}
__device__ __forceinline__ void gload16(const void* g, void* l) {
    __builtin_amdgcn_global_load_lds(
        (const __attribute__((address_space(1))) void*)g,
        (__attribute__((address_space(3))) void*)l, 16, 0, 0);
}

// ---------------------------------------------------------------------------
// f32 [R][K] -> hilo-packed bf16: row stride 2K ushorts, per 32-k slab:
// [32 hi | 32 lo].
__global__ __launch_bounds__(256)
void split_pack(const float* __restrict__ in, ushort* __restrict__ out,
                int R, int K)
{
    const int nch = R * (K >> 3);
    for (int i = blockIdx.x * 256 + threadIdx.x; i < nch; i += gridDim.x * 256) {
        const int row = i / (K >> 3);
        const int k8 = (i - row * (K >> 3)) * 8;
        const float4 v0 = *(const float4*)(in + (size_t)row * K + k8);
        const float4 v1 = *(const float4*)(in + (size_t)row * K + k8 + 4);
        float f[8] = {v0.x, v0.y, v0.z, v0.w, v1.x, v1.y, v1.z, v1.w};
        ushort h[8], l[8];
        #pragma unroll
        for (int j = 0; j < 8; j++) {
            h[j] = f2bf(f[j]);
            l[j] = f2bf(f[j] - bf2f(h[j]));
        }
        size_t o = (size_t)row * 2 * K + ((k8 >> 5) << 6) + (k8 & 31);
        *(ushort4*)(out + o)      = make_ushort4(h[0], h[1], h[2], h[3]);
        *(ushort4*)(out + o + 4)  = make_ushort4(h[4], h[5], h[6], h[7]);
        *(ushort4*)(out + o + 32) = make_ushort4(l[0], l[1], l[2], l[3]);
        *(ushort4*)(out + o + 36) = make_ushort4(l[4], l[5], l[6], l[7]);
    }
}

// W [Kd, Nn] f32 -> out [Nn][Kd]; PACK -> hilo-packed, else plain bf16.
template<bool PACK>
__global__ __launch_bounds__(256)
void transpose_cvt(const float* __restrict__ in, ushort* __restrict__ out,
                   int Kd, int Nn)
{
    __shared__ float tile[32][33];
    const int n0 = blockIdx.x * 32, k0 = blockIdx.y * 32;
    const int tx = threadIdx.x & 31, ty = threadIdx.x >> 5;
    #pragma unroll
    for (int r = 0; r < 4; r++)
        tile[ty + r * 8][tx] = in[(size_t)(k0 + ty + r * 8) * Nn + n0 + tx];
    __syncthreads();
    #pragma unroll
    for (int r = 0; r < 4; r++) {
        const float v = tile[tx][ty + r * 8];
        const int row = n0 + ty + r * 8, k = k0 + tx;
        if constexpr (PACK) {
            size_t o = (size_t)row * 2 * Kd + ((k >> 5) << 6) + (k & 31);
            ushort h = f2bf(v);
            out[o] = h;
            out[o + 32] = f2bf(v - bf2f(h));
        } else {
            out[(size_t)row * Kd + k] = f2bf(v);
        }
    }
}

// ||e_k||^2 per codebook row (L=256)
__global__ __launch_bounds__(64)
void colnorm(const float* __restrict__ pool, float* __restrict__ c)
{
    int r = blockIdx.x, lane = threadIdx.x;
    float4 v = *(const float4*)(pool + (size_t)r * 256 + lane * 4);
    float s = v.x * v.x + v.y * v.y + v.z * v.z + v.w * v.w;
    #pragma unroll
    for (int o = 32; o > 0; o >>= 1) s += __shfl_down(s, o);
    if (lane == 0) c[r] = s;
}

// ---------------------------------------------------------------------------
// Pipelined MFMA GEMM: C[M,Nn] = A[M,Kd] @ B^T, B given as [Nn,Kd].
// Tile TM x 128, 512 threads (8 waves). TM=256: waves 4x2 (wave 64x64);
// TM=128: waves 2x4 (wave 64x32). 3 LDS buffers, distance-2 prefetch,
// counted s_waitcnt vmcnt(N) + raw s_barrier. XCD-bijective block swizzle
// (requires nwg % 8 == 0 -- all launches satisfy this).
// SPLIT: BK=32 hilo slab; plain: BK=64.
// EPI: 0=+bias, 1=gelu(+bias), 2=sigmoid(+bias)+SSE, 3=VQ argmin partials.
template<int EPI, bool SPLIT, bool PACKOUT, int TM>
__global__ __launch_bounds__(512, 2)
void gemm_pipe(const ushort* __restrict__ A, const ushort* __restrict__ B,
               const float* __restrict__ bias, int Kd, int Nn,
               int rsA, int rsB,                    // row strides in BYTES
               ushort* __restrict__ Cu, float* __restrict__ Cf,
               const float* __restrict__ xref, float* __restrict__ ssePartial,
               float* __restrict__ pval, int* __restrict__ pidx)
{
    extern __shared__ ushort smem[];
    constexpr int AN   = (TM == 256) ? 4 : 2;       // n-fragments per wave
    constexpr int WCT  = (TM == 256) ? 64 : 32;     // wave column tile
    constexpr int ROWS = TM + 128;                  // LDS rows per buffer
    constexpr int BUFS = ROWS * 64;                 // ushorts per buffer

    const int tid = threadIdx.x;
    const int wave = tid >> 6, lane = tid & 63;

    // XCD-bijective swizzle (nwg % 8 == 0): XCD x owns contiguous tile range.
    const int nx = gridDim.x;
    const int nwg = nx * gridDim.y;
    const int orig = blockIdx.y * nx + blockIdx.x;
    const int wgid = (orig & 7) * (nwg >> 3) + (orig >> 3);
    const int bx = wgid % nx, by = wgid / nx;

    const int m0 = by * TM, n0 = bx * 128;
    const int wr = (TM == 256) ? (wave >> 1) : (wave >> 2);
    const int wc = (TM == 256) ? (wave & 1) : (wave & 3);
    const int fcol = lane & 15, kgrp = lane >> 4;
    const int NT = Kd / (SPLIT ? 32 : 64);

    const int srow = lane >> 3;                     // row within 8-row chunk
    const int sswz = ((lane & 7) ^ srow) << 4;      // swizzled src byte
    const char* Abase = (const char*)A + (size_t)m0 * rsA;
    const char* Bbase = (const char*)B + (size_t)n0 * rsB;

    f32x4 acc[4][AN];
    #pragma unroll
    for (int m = 0; m < 4; m++)
        #pragma unroll
        for (int n = 0; n < AN; n++)
            acc[m][n] = (f32x4){0.f, 0.f, 0.f, 0.f};

    auto STAGE = [&](int buf, int t) {
        ushort* dst = smem + buf * BUFS;
        const size_t kb = (size_t)t * 128;
        #pragma unroll
        for (int g = 0; g < TM / 64; g++) {
            const int rb = g * 64 + wave * 8;
            gload16(Abase + (size_t)(rb + srow) * rsA + kb + sswz, dst + rb * 64);
        }
        #pragma unroll
        for (int g = 0; g < 2; g++) {
            const int rb = g * 64 + wave * 8;
            gload16(Bbase + (size_t)(rb + srow) * rsB + kb + sswz,
                    dst + (TM + rb) * 64);
        }
    };
    auto LD = [&](int buf, int r, int u) -> s16x8 {
        return *(const s16x8*)(smem + buf * BUFS + r * 64 + ((u ^ (r & 7)) << 3));
    };

    STAGE(0, 0);
    STAGE(1, 1);
    for (int t = 0; t < NT; ++t) {
        if (t + 1 < NT) {
            if constexpr (TM == 256) asm volatile("s_waitcnt vmcnt(6)" ::: "memory");
            else                     asm volatile("s_waitcnt vmcnt(4)" ::: "memory");
        } else {
            asm volatile("s_waitcnt vmcnt(0)" ::: "memory");
        }
        __builtin_amdgcn_s_barrier();
        if (t + 2 < NT) STAGE((t + 2) % 3, t + 2);
        const int buf = t % 3;
        if constexpr (SPLIT) {
            s16x8 aH[4], aL[4], bH[AN], bL[AN];
            #pragma unroll
            for (int m = 0; m < 4; m++) {
                const int r = wr * 64 + m * 16 + fcol;
                aH[m] = LD(buf, r, kgrp);
                aL[m] = LD(buf, r, 4 + kgrp);
            }
            #pragma unroll
            for (int n = 0; n < AN; n++) {
                const int r = TM + wc * WCT + n * 16 + fcol;
                bH[n] = LD(buf, r, kgrp);
                bL[n] = LD(buf, r, 4 + kgrp);
            }
            __builtin_amdgcn_s_setprio(1);
            #pragma unroll
            for (int m = 0; m < 4; m++)
                #pragma unroll
                for (int n = 0; n < AN; n++) {
                    acc[m][n] = __builtin_amdgcn_mfma_f32_16x16x32_bf16(aH[m], bH[n], acc[m][n], 0, 0, 0);
                    acc[m][n] = __builtin_amdgcn_mfma_f32_16x16x32_bf16(aH[m], bL[n], acc[m][n], 0, 0, 0);
                    acc[m][n] = __builtin_amdgcn_mfma_f32_16x16x32_bf16(aL[m], bH[n], acc[m][n], 0, 0, 0);
                }
            __builtin_amdgcn_s_setprio(0);
        } else {
            #pragma unroll
            for (int ks = 0; ks < 2; ks++) {
                s16x8 a[4], b[AN];
                #pragma unroll
                for (int m = 0; m < 4; m++)
                    a[m] = LD(buf, wr * 64 + m * 16 + fcol, ks * 4 + kgrp);
                #pragma unroll
                for (int n = 0; n < AN; n++)
                    b[n] = LD(buf, TM + wc * WCT + n * 16 + fcol, ks * 4 + kgrp);
                __builtin_amdgcn_s_setprio(1);
                #pragma unroll
                for (int m = 0; m < 4; m++)
                    #pragma unroll
                    for (int n = 0; n < AN; n++)
                        acc[m][n] = __builtin_amdgcn_mfma_f32_16x16x32_bf16(a[m], b[n], acc[m][n], 0, 0, 0);
                __builtin_amdgcn_s_setprio(0);
            }
        }
    }
    __builtin_amdgcn_sched_barrier(0);

    // ------------------------------ epilogue ------------------------------
    int colg[AN];
    float bcol[AN];
    #pragma unroll
    for (int n = 0; n < AN; n++) {
        colg[n] = n0 + wc * WCT + n * 16 + fcol;
        bcol[n] = bias[colg[n]];
    }

    if constexpr (EPI == 0 || EPI == 1) {
        #pragma unroll
        for (int m = 0; m < 4; m++)
            #pragma unroll
            for (int v = 0; v < 4; v++) {
                const int row = m0 + wr * 64 + m * 16 + kgrp * 4 + v;
                #pragma unroll
                for (int n = 0; n < AN; n++) {
                    float val = acc[m][n][v] + bcol[n];
                    if (EPI == 1) val = gelu_f(val);
                    if constexpr (PACKOUT) {
                        size_t o = (size_t)row * 2 * Nn + ((colg[n] >> 5) << 6) + (colg[n] & 31);
                        ushort h = f2bf(val);
                        Cu[o] = h;
                        Cu[o + 32] = f2bf(val - bf2f(h));
                    } else {
                        Cu[(size_t)row * Nn + colg[n]] = f2bf(val);
                    }
                }
            }
    } else if constexpr (EPI == 2) {
        float lsse = 0.0f;
        #pragma unroll
        for (int m = 0; m < 4; m++)
            #pragma unroll
            for (int v = 0; v < 4; v++) {
                const int row = m0 + wr * 64 + m * 16 + kgrp * 4 + v;
                const size_t rb = (size_t)row * Nn;
                #pragma unroll
                for (int n = 0; n < AN; n++) {
                    float val = acc[m][n][v] + bcol[n];
                    val = 1.0f / (1.0f + expf(-val));
                    __builtin_nontemporal_store(val, &Cf[rb + colg[n]]);
                    float d = xref[rb + colg[n]] - val;
                    lsse += d * d;
                }
            }
        __syncthreads();
        float* red = (float*)smem;
        red[tid] = lsse;
        __syncthreads();
        for (int s = 256; s > 0; s >>= 1) {
            if (tid < s) red[tid] += red[tid + s];
            __syncthreads();
        }
        if (tid == 0) ssePartial[by * gridDim.x + bx] = red[0];
    } else if constexpr (EPI == 3) {
        __syncthreads();
        float* sv = (float*)smem;            // [2][256]
        int*   si = (int*)(sv + 512);
        #pragma unroll
        for (int m = 0; m < 4; m++)
            #pragma unroll
            for (int v = 0; v < 4; v++) {
                float best = INFINITY;
                int bidx = 0x7fffffff;
                #pragma unroll
                for (int n = 0; n < AN; n++) {
                    float sc = bcol[n] - 2.0f * acc[m][n][v];
                    if (sc < best || (sc == best && colg[n] < bidx)) { best = sc; bidx = colg[n]; }
                }
                #pragma unroll
                for (int d = 1; d < 16; d <<= 1) {
                    float ov = __shfl_xor(best, d, 64);
                    int   oi = __shfl_xor(bidx, d, 64);
                    if (ov < best || (ov == best && oi < bidx)) { best = ov; bidx = oi; }
                }
                if (fcol == 0) {
                    const int rl = wr * 64 + m * 16 + kgrp * 4 + v;
                    sv[wc * 256 + rl] = best;
                    si[wc * 256 + rl] = bidx;
                }
            }
        __syncthreads();
        if (tid < 256) {
            float v0 = sv[tid], v1 = sv[256 + tid];
            int   i0 = si[tid], i1 = si[256 + tid];
            if (v1 < v0 || (v1 == v0 && i1 < i0)) { v0 = v1; i0 = i1; }
            pval[(size_t)(m0 + tid) * gridDim.x + bx] = v0;
            pidx[(size_t)(m0 + tid) * gridDim.x + bx] = i0;
        }
    }
}

// ---------------------------------------------------------------------------
// 4 rows per block: reduce 32 block partials -> kbest; one-hot (nontemporal);
// gather z_q; VQ partial.
__global__ __launch_bounds__(256)
void argmin_final(const float* __restrict__ pval, const int* __restrict__ pidx,
                  int nblk, const ushort* __restrict__ zEp,
                  const float* __restrict__ pool,
                  float* __restrict__ zdisc, ushort* __restrict__ zq,
                  float* __restrict__ vqP)
{
    const int t = threadIdx.x;
    const int r = blockIdx.x * 4 + (t >> 6);
    const int l = t & 63;

    float best = INFINITY;
    int bi = 0x7fffffff;
    if (l < nblk) {
        best = pval[(size_t)r * nblk + l];
        bi = pidx[(size_t)r * nblk + l];
    }
    #pragma unroll
    for (int d = 32; d > 0; d >>= 1) {
        float ov = __shfl_xor(best, d, 64);
        int   oi = __shfl_xor(bi, d, 64);
        if (ov < best || (ov == best && oi < bi)) { best = ov; bi = oi; }
    }
    const int kbest = bi;

    f32x4* zrow = (f32x4*)(zdisc + (size_t)r * 4096);
    #pragma unroll
    for (int it = 0; it < 16; it++) {
        const int j = it * 64 + l;
        f32x4 o = (f32x4){0.f, 0.f, 0.f, 0.f};
        if ((kbest >> 2) == j) o[kbest & 3] = 1.0f;
        __builtin_nontemporal_store(o, &zrow[j]);
    }

    const float4 pz = *(const float4*)(pool + (size_t)kbest * 256 + l * 4);
    *(ushort4*)(zq + (size_t)r * 256 + l * 4) =
        make_ushort4(f2bf(pz.x), f2bf(pz.y), f2bf(pz.z), f2bf(pz.w));
    const size_t zo = (size_t)r * 512 + (((l * 4) >> 5) << 6) + ((l * 4) & 31);
    const ushort4 zh = *(const ushort4*)(zEp + zo);
    const ushort4 zl = *(const ushort4*)(zEp + zo + 32);
    float d0 = bf2f(zh.x) + bf2f(zl.x) - pz.x;
    float d1 = bf2f(zh.y) + bf2f(zl.y) - pz.y;
    float d2 = bf2f(zh.z) + bf2f(zl.z) - pz.z;
    float d3 = bf2f(zh.w) + bf2f(zl.w) - pz.w;
    float s = d0 * d0 + d1 * d1 + d2 * d2 + d3 * d3;
    #pragma unroll
    for (int o = 32; o > 0; o >>= 1) s += __shfl_xor(s, o, 64);
    if (l == 0) vqP[r] = s;
}

__global__ __launch_bounds__(256)
void loss_final(const float* __restrict__ sseP, int nP,
                const float* __restrict__ vqP, int nV,
                float* __restrict__ out)
{
    int tid = threadIdx.x;
    float sx = 0.0f, svq = 0.0f;
    for (int i = tid; i < nP; i += 256) sx += sseP[i];
    for (int i = tid; i < nV; i += 256) svq += vqP[i];
    __shared__ float a[256], b[256];
    a[tid] = sx; b[tid] = svq;
    __syncthreads();
    for (int s = 128; s > 0; s >>= 1) {
        if (tid < s) { a[tid] += a[tid + s]; b[tid] += b[tid + s]; }
        __syncthreads();
    }
    if (tid == 0) out[0] = (a[0] + 1.25f * b[0]) / 16384.0f;
}

// ---------------------------------------------------------------------------
extern "C" void kernel_launch(void* const* d_in, const int* in_sizes, int n_in,
                              void* d_out, int out_size, void* d_ws, size_t ws_size,
                              hipStream_t stream)
{
    const float* x    = (const float*)d_in[0];
    const float* pool = (const float*)d_in[1];
    const float* ew1  = (const float*)d_in[2];
    const float* eb1  = (const float*)d_in[3];
    const float* ew2  = (const float*)d_in[4];
    const float* eb2  = (const float*)d_in[5];
    const float* ew3  = (const float*)d_in[6];
    const float* eb3  = (const float*)d_in[7];
    const float* dw1  = (const float*)d_in[8];
    const float* db1  = (const float*)d_in[9];
    const float* dw2  = (const float*)d_in[10];
    const float* db2  = (const float*)d_in[11];
    const float* dw3  = (const float*)d_in[12];
    const float* db3  = (const float*)d_in[13];

    const int N = 16384, D = 1024, H = 1024, L = 256, K = 4096;

    float* out   = (float*)d_out;
    float* xpred = out;
    float* zdisc = out + (size_t)N * D;
    float* lossp = zdisc + (size_t)N * K;

    char* ws = (char*)d_ws;
    ushort* xp    = (ushort*)(ws + 0 * MB);    // 64MB packed x
    ushort* h1p   = (ushort*)(ws + 64 * MB);   // 64MB
    ushort* h2p   = (ushort*)(ws + 128 * MB);  // 64MB
    ushort* zEp   = (ushort*)(ws + 192 * MB);  // 16MB
    ushort* zq    = (ushort*)(ws + 208 * MB);  // 8MB plain bf16
    ushort* poolp = (ushort*)(ws + 216 * MB);  // 4MB
    ushort* w1p   = (ushort*)(ws + 220 * MB);  // 4MB
    ushort* w2p   = (ushort*)(ws + 224 * MB);  // 4MB
    ushort* w3p   = (ushort*)(ws + 228 * MB);  // 1MB
    ushort* v1    = (ushort*)(ws + 229 * MB);  // 0.5MB plain
    ushort* v2    = (ushort*)(ws + 230 * MB);  // 2MB
    ushort* v3    = (ushort*)(ws + 232 * MB);  // 2MB
    ushort* h3    = (ushort*)(ws + 240 * MB);  // 32MB plain
    ushort* h4    = (ushort*)(ws + 272 * MB);  // 32MB
    float*  cn    = (float*)(ws + 304 * MB);   // 16KB
    float*  pv    = (float*)(ws + 305 * MB);   // 2MB
    int*    pi    = (int*)(ws + 307 * MB);     // 2MB
    float*  vqP   = (float*)(ws + 309 * MB);   // 64KB
    float*  sxP   = (float*)(ws + 310 * MB);   // 4KB

    const int SH256 = 3 * (384 * 64) * 2;      // 147456 B
    const int SH128 = 3 * (256 * 64) * 2;      // 98304 B
    (void)hipFuncSetAttribute((const void*)gemm_pipe<1, true, true, 256>,
        hipFuncAttributeMaxDynamicSharedMemorySize, SH256);
    (void)hipFuncSetAttribute((const void*)gemm_pipe<0, true, true, 128>,
        hipFuncAttributeMaxDynamicSharedMemorySize, SH128);
    (void)hipFuncSetAttribute((const void*)gemm_pipe<3, true, false, 256>,
        hipFuncAttributeMaxDynamicSharedMemorySize, SH256);
    (void)hipFuncSetAttribute((const void*)gemm_pipe<1, false, false, 256>,
        hipFuncAttributeMaxDynamicSharedMemorySize, SH256);
    (void)hipFuncSetAttribute((const void*)gemm_pipe<2, false, false, 256>,
        hipFuncAttributeMaxDynamicSharedMemorySize, SH256);

    dim3 blk(256), gblk(512);

    // prep
    split_pack<<<2048, blk, 0, stream>>>(x, xp, N, D);
    split_pack<<<512, blk, 0, stream>>>(pool, poolp, K, L);
    colnorm<<<K, 64, 0, stream>>>(pool, cn);
    transpose_cvt<true><<<dim3(H / 32, D / 32), blk, 0, stream>>>(ew1, w1p, D, H);
    transpose_cvt<true><<<dim3(H / 32, H / 32), blk, 0, stream>>>(ew2, w2p, H, H);
    transpose_cvt<true><<<dim3(L / 32, H / 32), blk, 0, stream>>>(ew3, w3p, H, L);
    transpose_cvt<false><<<dim3(H / 32, L / 32), blk, 0, stream>>>(dw1, v1, L, H);
    transpose_cvt<false><<<dim3(H / 32, H / 32), blk, 0, stream>>>(dw2, v2, H, H);
    transpose_cvt<false><<<dim3(D / 32, H / 32), blk, 0, stream>>>(dw3, v3, H, D);

    // encoder (split, packed in/out)
    gemm_pipe<1, true, true, 256><<<dim3(H / 128, N / 256), gblk, SH256, stream>>>(
        xp, w1p, eb1, D, H, 2 * D * 2, 2 * D * 2, h1p, nullptr, nullptr, nullptr, nullptr, nullptr);
    gemm_pipe<1, true, true, 256><<<dim3(H / 128, N / 256), gblk, SH256, stream>>>(
        h1p, w2p, eb2, H, H, 2 * H * 2, 2 * H * 2, h2p, nullptr, nullptr, nullptr, nullptr, nullptr);
    // enc3: TM=128 -> 256 blocks (full GPU)
    gemm_pipe<0, true, true, 128><<<dim3(L / 128, N / 128), gblk, SH128, stream>>>(
        h2p, w3p, eb3, H, L, 2 * H * 2, 2 * H * 2, zEp, nullptr, nullptr, nullptr, nullptr, nullptr);

    // VQ scores + fused per-block argmin (split)
    gemm_pipe<3, true, false, 256><<<dim3(K / 128, N / 256), gblk, SH256, stream>>>(
        zEp, poolp, cn, L, K, 2 * L * 2, 2 * L * 2, nullptr, nullptr, nullptr, nullptr, pv, pi);

    argmin_final<<<N / 4, blk, 0, stream>>>(pv, pi, K / 128, zEp, pool, zdisc, zq, vqP);

    // decoder (plain bf16)
    gemm_pipe<1, false, false, 256><<<dim3(H / 128, N / 256), gblk, SH256, stream>>>(
        zq, v1, db1, L, H, L * 2, L * 2, h3, nullptr, nullptr, nullptr, nullptr, nullptr);
    gemm_pipe<1, false, false, 256><<<dim3(H / 128, N / 256), gblk, SH256, stream>>>(
        h3, v2, db2, H, H, H * 2, H * 2, h4, nullptr, nullptr, nullptr, nullptr, nullptr);
    gemm_pipe<2, false, false, 256><<<dim3(D / 128, N / 256), gblk, SH256, stream>>>(
        h4, v3, db3, H, D, H * 2, H * 2, nullptr, xpred, x, sxP, nullptr, nullptr);

    loss_final<<<1, blk, 0, stream>>>(sxP, (D / 128) * (N / 256), vqP, N, lossp);
}